// Round 6
// baseline (300.082 us; speedup 1.0000x reference)
//
#include <hip/hip_runtime.h>

// GAT 2-layer, N=100000 nodes, E=1.6M edges, dims 128->64->64, all fp32.
// Strategy:
//   - s[i] = a[i]·we collapses edge-logit GEMV to per-node scalar (We is [1,64]).
//   - tanh-bounded logits => skip segment_max (exp ratio identical).
//   - CSR build: coarse 128-node-bin counting sort + per-bin in-LDS sort.
//     R9: within-node DETERMINISTIC order (rank-sort by dst).
//   - k_node v2 (R13): register-stationary W frags, pre-converted bf16 hi/lo
//     LDS x-tile; inner loop = ds_read_b128 + MFMA only.
//   - k_aggr v9 (R14): R5 showed waves >90% stalled; P(deg>16)=0.43 means the
//     serial extra-chunk path ran for ~89% of groups, killing v7's pipeline.
//     Now ONE 32-edge burst per node (two 16-gather bursts, second skipped
//     wave-uniformly when all 4 nodes have deg<=16; deg>32 fallback ~2e-5):
//       * up to 32 outstanding gathers per wave, no serial mid-group chain
//       * both edge-slots' col + s[col] prefetched one group ahead
//       * 1024 blocks: all resident at 4 waves/SIMD, balanced 6-7 groups/wave
//       * per-node accumulation order unchanged -> bitwise deterministic

#define WS_ALIGN 256
#define BIN_SHIFT 7
#define BIN_NODES 128
#define BIN_CAP 2560   // mean bin count 2048, sigma ~44 -> +11.6 sigma margin
#define MAX_BINS 1024
#define EPB 4096       // edges per k_bin block
#define AGGR_BLOCKS 1024

typedef __attribute__((ext_vector_type(8))) short short8;
typedef __attribute__((ext_vector_type(4))) short short4_t;
typedef __attribute__((ext_vector_type(4))) float f32x4;

__device__ __forceinline__ float fast_tanh(float x) {
  x = fminf(15.f, fmaxf(-15.f, x));
  float e = __expf(2.f * x);
  return (e - 1.f) * __builtin_amdgcn_rcpf(e + 1.f);
}

__device__ __forceinline__ unsigned short f32_to_bf16_rne(float f) {
  unsigned u = __float_as_uint(f);
  unsigned r = u + 0x7fffu + ((u >> 16) & 1u);
  return (unsigned short)(r >> 16);
}

// Split one element of [Wa;Wv] into bf16 hi/lo, FRAGMENT-LINEAR layout:
// i = (((nt*KBLK + kb)*4 + q)*16 + c)*8 + j  <->  W[nt*16+c][kb*32+q*8+j].
__device__ __forceinline__ void prepw_one(const float* __restrict__ Wa,
                                          const float* __restrict__ Wv,
                                          short* __restrict__ Wh, short* __restrict__ Wl,
                                          int K, int i) {
  int KBLK = K / 32;
  int j = i & 7;
  int c = (i >> 3) & 15;
  int q = (i >> 7) & 3;
  int r = i >> 9;  // nt*KBLK + kb
  int nt = r / KBLK, kb = r - nt * KBLK;
  int row = nt * 16 + c;
  int col = kb * 32 + q * 8 + j;
  float f = (row < 64) ? Wa[row * K + col] : Wv[(row - 64) * K + col];
  unsigned u = __float_as_uint(f);
  float hf = __uint_as_float(u & 0xffff0000u);
  Wh[i] = (short)(u >> 16);
  Wl[i] = (short)(__float_as_uint(f - hf) >> 16);
}

// Fused setup: weight prep for both layers + cursor init (one launch).
__global__ void k_setup(const float* __restrict__ W11, const float* __restrict__ W13,
                        short* __restrict__ Wh1, short* __restrict__ Wl1,
                        const float* __restrict__ W21, const float* __restrict__ W23,
                        short* __restrict__ Wh2, short* __restrict__ Wl2,
                        int* __restrict__ cursor, int nb) {
  int i = blockIdx.x * 256 + threadIdx.x;
  if (i < 16384) {
    prepw_one(W11, W13, Wh1, Wl1, 128, i);
  } else if (i < 16384 + 8192) {
    prepw_one(W21, W23, Wh2, Wl2, 64, i - 16384);
  } else {
    int b = i - 24576;
    if (b < nb) cursor[b] = b * BIN_CAP;
  }
}

// Coarse counting-sort of edges into 128-node bins.
__global__ __launch_bounds__(256) void k_bin(const int* __restrict__ src,
                                             const int* __restrict__ dst,
                                             int* __restrict__ cursor,
                                             int* __restrict__ binned, int E, int nb) {
  __shared__ int ssrc[EPB];
  __shared__ int sdst[EPB];
  __shared__ int hist[MAX_BINS];
  __shared__ int base[MAX_BINS];
  int t = threadIdx.x;
  for (int i = t; i < nb; i += 256) hist[i] = 0;
  __syncthreads();
  int e0 = blockIdx.x * EPB;
  for (int i = t; i < EPB; i += 256) {
    int e = e0 + i;
    int sv = -1, dv = 0;
    if (e < E) {
      sv = src[e];
      dv = dst[e];
      atomicAdd(&hist[sv >> BIN_SHIFT], 1);
    }
    ssrc[i] = sv;
    sdst[i] = dv;
  }
  __syncthreads();
  for (int b = t; b < nb; b += 256) {
    int c = hist[b];
    base[b] = c ? atomicAdd(&cursor[b], c) : 0;
    hist[b] = 0;
  }
  __syncthreads();
  for (int i = t; i < EPB; i += 256) {
    int sv = ssrc[i];
    if (sv >= 0) {
      int b = sv >> BIN_SHIFT;
      int r = atomicAdd(&hist[b], 1);
      int pos = base[b] + r;
      if (pos < (b + 1) * BIN_CAP)  // overflow guard (never expected to fire)
        binned[pos] = (sdst[i] << BIN_SHIFT) | (sv & (BIN_NODES - 1));
    }
  }
}

// One block per bin: group by src-within-bin in LDS (counting sort), then
// DETERMINISTIC rank-sort of each node's segment by dst (atomic scatter order
// is launch-dependent; sorted multiset is not). Coalesced write-back of
// dst-only values, emit per-node [rs, re).
__global__ __launch_bounds__(256) void k_sort_bin(int* __restrict__ binned,
                                                  const int* __restrict__ cursor,
                                                  int* __restrict__ rs,
                                                  int* __restrict__ re, int n) {
  __shared__ int ents[BIN_CAP];    // input pk; reused as rank-sorted dst output
  __shared__ int sorted[BIN_CAP];  // node-grouped pk
  __shared__ int hist[BIN_NODES];
  __shared__ int scan[BIN_NODES];
  __shared__ int cur[BIN_NODES];
  int bin = blockIdx.x;
  int t = threadIdx.x;
  int nbase = bin << BIN_SHIFT;
  int cnt = cursor[bin] - bin * BIN_CAP;
  if (cnt > BIN_CAP) cnt = BIN_CAP;
  if (t < BIN_NODES) hist[t] = 0;
  __syncthreads();
  int* bp = binned + (size_t)bin * BIN_CAP;
  for (int i = t; i < cnt; i += 256) {
    int pk = bp[i];
    ents[i] = pk;
    atomicAdd(&hist[pk & (BIN_NODES - 1)], 1);
  }
  __syncthreads();
  if (t < BIN_NODES) scan[t] = hist[t];
  __syncthreads();
  for (int off = 1; off < BIN_NODES; off <<= 1) {
    int add = (t < BIN_NODES && t >= off) ? scan[t - off] : 0;
    __syncthreads();
    if (t < BIN_NODES) scan[t] += add;
    __syncthreads();
  }
  if (t < BIN_NODES) {
    int ex = scan[t] - hist[t];  // exclusive
    cur[t] = ex;
    int node = nbase + t;
    if (node < n) {
      rs[node] = bin * BIN_CAP + ex;
      re[node] = bin * BIN_CAP + ex + hist[t];
    }
  }
  __syncthreads();
  // scatter by node (keep full pk — needed for the rank pass)
  for (int i = t; i < cnt; i += 256) {
    int pk = ents[i];
    int pos = atomicAdd(&cur[pk & (BIN_NODES - 1)], 1);
    sorted[pos] = pk;
  }
  __syncthreads();
  // deterministic rank-sort within each node segment, ascending by dst.
  for (int i = t; i < cnt; i += 256) {
    int pk = sorted[i];
    int node = pk & (BIN_NODES - 1);
    int hi = scan[node];
    int lo = hi - hist[node];
    int r = lo;
    for (int j = lo; j < hi; j++) {
      int pj = sorted[j];
      r += (pj < pk) || (pj == pk && j < i);
    }
    ents[r] = pk >> BIN_SHIFT;  // keep dst only
  }
  __syncthreads();
  for (int i = t; i < cnt; i += 256) bp[i] = ents[i];  // coalesced write-back
}

// MFMA node kernel v2: D[node][0..127] = x[node][:] @ [Wa;Wv]^T, 16x16x32 bf16.
// Block = 256 thr / 4 waves / 64 nodes. Wave w owns output n-tiles {2w,2w+1}
// (32 dims) with W frags REGISTER-STATIONARY (one-time coalesced loads);
// iterates 4 node-subtiles from a pre-converted bf16 hi/lo LDS x-tile
// (+8-short row pad -> only free 2-way conflicts on ds_read_b128).
// Waves 0,1 hold a-dims -> partial s, combined via sP LDS; waves 2,3 write v.
template <int K>
__global__ __launch_bounds__(256) void k_node(
    const float* __restrict__ x, const short* __restrict__ Wh,
    const short* __restrict__ Wl, const float* __restrict__ ba,
    const float* __restrict__ we, const float* __restrict__ bv,
    unsigned short* __restrict__ v_out, float* __restrict__ s_out, int n) {
  constexpr int KBLK = K / 32;
  constexpr int RS = K + 8;  // shorts per LDS row (+16B pad)
  __shared__ short sah[64 * RS];
  __shared__ short sal[64 * RS];
  __shared__ float sP[2][64];
  int t = threadIdx.x;
  int l = t & 63;
  int w = t >> 6;
  int q = l >> 4, c = l & 15;
  int node0b = blockIdx.x * 64;

  // stage x tile: coalesced float4 read -> bf16 hi/lo split -> LDS
  {
    const float4* xg = (const float4*)(x + (size_t)node0b * K);
    constexpr int R4 = K / 4;
#pragma unroll
    for (int it = 0; it < 64 * R4 / 256; it++) {
      int i = it * 256 + t;
      int r = i / R4, k4 = i - r * R4;
      float4 val = (node0b + r < n) ? xg[i] : (float4){0.f, 0.f, 0.f, 0.f};
      float xv[4] = {val.x, val.y, val.z, val.w};
      short4_t hi, lo;
#pragma unroll
      for (int j = 0; j < 4; j++) {
        unsigned u = __float_as_uint(xv[j]);
        hi[j] = (short)(u >> 16);
        float hf = __uint_as_float(u & 0xffff0000u);
        lo[j] = (short)(__float_as_uint(xv[j] - hf) >> 16);
      }
      *(short4_t*)&sah[r * RS + k4 * 4] = hi;
      *(short4_t*)&sal[r * RS + k4 * 4] = lo;
    }
  }

  // one-time W fragment loads (register-stationary), overlap staging wait
  const short8* WhF = (const short8*)Wh;
  const short8* WlF = (const short8*)Wl;
  short8 wfh[2][KBLK], wfl[2][KBLK];
#pragma unroll
  for (int mt = 0; mt < 2; mt++)
#pragma unroll
    for (int kb = 0; kb < KBLK; kb++) {
      size_t f = (size_t)((2 * w + mt) * KBLK + kb) * 64 + l;
      wfh[mt][kb] = WhF[f];
      wfl[mt][kb] = WlF[f];
    }
  __syncthreads();

  f32x4 acc[4][2];
#pragma unroll
  for (int ns = 0; ns < 4; ns++)
#pragma unroll
    for (int mt = 0; mt < 2; mt++) acc[ns][mt] = (f32x4){0.f, 0.f, 0.f, 0.f};

#pragma unroll
  for (int ns = 0; ns < 4; ns++) {
#pragma unroll
    for (int kb = 0; kb < KBLK; kb++) {
      int off = (ns * 16 + c) * RS + kb * 32 + q * 8;
      short8 ah = *(const short8*)&sah[off];
      short8 al = *(const short8*)&sal[off];
#pragma unroll
      for (int mt = 0; mt < 2; mt++) {
        acc[ns][mt] = __builtin_amdgcn_mfma_f32_16x16x32_bf16(ah, wfh[mt][kb], acc[ns][mt], 0, 0, 0);
        acc[ns][mt] = __builtin_amdgcn_mfma_f32_16x16x32_bf16(ah, wfl[mt][kb], acc[ns][mt], 0, 0, 0);
        acc[ns][mt] = __builtin_amdgcn_mfma_f32_16x16x32_bf16(al, wfh[mt][kb], acc[ns][mt], 0, 0, 0);
      }
    }
  }

  // ---- epilogue ----
  if (w < 2) {
    // a-dims: partial s over this wave's 32 dims
    float bav0 = ba[w * 32 + c], wev0 = we[w * 32 + c];
    float bav1 = ba[w * 32 + 16 + c], wev1 = we[w * 32 + 16 + c];
#pragma unroll
    for (int ns = 0; ns < 4; ns++) {
#pragma unroll
      for (int r = 0; r < 4; r++) {
        float pv = fast_tanh(acc[ns][0][r] + bav0) * wev0 +
                   fast_tanh(acc[ns][1][r] + bav1) * wev1;
#pragma unroll
        for (int mm = 1; mm < 16; mm <<= 1) pv += __shfl_xor(pv, mm, 64);
        if (c == 0) sP[w][ns * 16 + q * 4 + r] = pv;
      }
    }
  } else {
    // v-dims: write bf16 v
    int wv = w - 2;
    float bvv0 = bv[wv * 32 + c], bvv1 = bv[wv * 32 + 16 + c];
#pragma unroll
    for (int ns = 0; ns < 4; ns++) {
#pragma unroll
      for (int r = 0; r < 4; r++) {
        int node = node0b + ns * 16 + q * 4 + r;
        if (node < n) {
          v_out[(size_t)node * 64 + wv * 32 + c] =
              f32_to_bf16_rne(fast_tanh(acc[ns][0][r] + bvv0));
          v_out[(size_t)node * 64 + wv * 32 + 16 + c] =
              f32_to_bf16_rne(fast_tanh(acc[ns][1][r] + bvv1));
        }
      }
    }
  }
  __syncthreads();
  if (t < 64) {
    int node = node0b + t;
    if (node < n) s_out[node] = sP[0][t] + sP[1][t];
  }
}

// k_aggr v9: 4 nodes per wave, lane = (node-slot q=l>>4, dim-group g=l&15).
// Per group ONE 32-edge-per-node burst: gathers for edges 0..15 always, edges
// 16..31 when any node in the wave needs them (wave-uniform); up to 32
// outstanding v-row gathers. Both slots' col + s[col] prefetched one group
// ahead. deg>32 fallback (~2e-5 of nodes) keeps exact accumulation order.
__global__ __launch_bounds__(256, 4) void k_aggr(const int* __restrict__ rs,
                                                 const int* __restrict__ re,
                                                 const int* __restrict__ col,
                                                 const float* __restrict__ s,
                                                 const float* __restrict__ be_p,
                                                 const unsigned short* __restrict__ v,
                                                 float* __restrict__ out, int n) {
  int wid = (int)((blockIdx.x * 256 + threadIdx.x) >> 6);
  int nwv = (int)gridDim.x * 4;
  int l = threadIdx.x & 63;
  int q = l >> 4;  // node slot 0..3
  int g = l & 15;  // dim group: dims g*4 .. g*4+3 ; also edge sub-index
  int qb = l & 48; // quarter base lane
  float be = be_p[0];
  int ngroups = (n + 3) >> 2;
  if (wid >= ngroups) return;

  // prefetched state for the current group (meta, both edge slots)
  int ce0, ce1;
  float csrow, csc0, csc1;
  int cc0, cc1;
  {
    int node = wid * 4 + q;
    bool vn = node < n;
    ce0 = vn ? rs[node] : 0;
    ce1 = vn ? re[node] : 0;
    csrow = vn ? s[node] : 0.f;
    int m = ce1 - ce0;
    cc0 = (g < m) ? col[ce0 + g] : 0;
    cc1 = (g + 16 < m) ? col[ce0 + g + 16] : 0;
    csc0 = (g < m) ? s[cc0] : 0.f;
    csc1 = (g + 16 < m) ? s[cc1] : 0.f;
  }

  for (int grp = wid; grp < ngroups; grp += nwv) {
    int m = ce1 - ce0;
    int e0 = ce0;
    float srow = csrow;
    bool two = __any(m > 16);  // wave-uniform: second burst needed?

    // burst 1: edges 0..15 of each node (16 gathers in flight)
    uint2 pv[16];
#pragma unroll
    for (int jj = 0; jj < 16; jj++) {
      int cj = __shfl(cc0, qb + jj, 64);
      pv[jj] = *(const uint2*)(v + ((size_t)cj << 6) + (g << 2));
    }
    // burst 2: edges 16..31 (guard lanes pull row 0 -> cached, w=0)
    uint2 pw[16];
    if (two) {
#pragma unroll
      for (int jj = 0; jj < 16; jj++) {
        int cj = __shfl(cc1, qb + jj, 64);
        pw[jj] = *(const uint2*)(v + ((size_t)cj << 6) + (g << 2));
      }
    }

    // weights for both slots (overlaps gather returns)
    float w0 = (g < m) ? __expf(fast_tanh(srow + csc0 + be)) : 0.f;
    float w1 = (g + 16 < m) ? __expf(fast_tanh(srow + csc1 + be)) : 0.f;
    float dl = w0 + w1;

    // prefetch next group's meta + cols + s[col] (overlaps consume)
    int nxt = grp + nwv;
    if (nxt < ngroups) {
      int node = nxt * 4 + q;
      bool vn = node < n;
      ce0 = vn ? rs[node] : 0;
      ce1 = vn ? re[node] : 0;
      csrow = vn ? s[node] : 0.f;
      int nm = ce1 - ce0;
      cc0 = (g < nm) ? col[ce0 + g] : 0;
      cc1 = (g + 16 < nm) ? col[ce0 + g + 16] : 0;
      csc0 = (g < nm) ? s[cc0] : 0.f;
      csc1 = (g + 16 < nm) ? s[cc1] : 0.f;
    }

    // consume burst 1 (edges 0..15, in order)
    float a0 = 0.f, a1 = 0.f, a2 = 0.f, a3 = 0.f;
#pragma unroll
    for (int jj = 0; jj < 16; jj++) {
      float wj = __shfl(w0, qb + jj, 64);
      a0 = fmaf(wj, __uint_as_float(pv[jj].x << 16), a0);
      a1 = fmaf(wj, __uint_as_float(pv[jj].x & 0xffff0000u), a1);
      a2 = fmaf(wj, __uint_as_float(pv[jj].y << 16), a2);
      a3 = fmaf(wj, __uint_as_float(pv[jj].y & 0xffff0000u), a3);
    }
    // consume burst 2 (edges 16..31, in order)
    if (two) {
#pragma unroll
      for (int jj = 0; jj < 16; jj++) {
        float wj = __shfl(w1, qb + jj, 64);
        a0 = fmaf(wj, __uint_as_float(pw[jj].x << 16), a0);
        a1 = fmaf(wj, __uint_as_float(pw[jj].x & 0xffff0000u), a1);
        a2 = fmaf(wj, __uint_as_float(pw[jj].y << 16), a2);
        a3 = fmaf(wj, __uint_as_float(pw[jj].y & 0xffff0000u), a3);
      }
    }
    // fallback for deg>32 (vanishingly rare; keeps exact order)
    for (int cb = 32; !__all(m - cb <= 0); cb += 16) {
      bool act = (cb + g) < m;
      int c = act ? col[e0 + cb + g] : 0;
      float wx = act ? __expf(fast_tanh(srow + s[c] + be)) : 0.f;
      dl += wx;
#pragma unroll
      for (int jj = 0; jj < 16; jj++) {
        int cj = __shfl(c, qb + jj, 64);
        float wj = __shfl(wx, qb + jj, 64);
        uint2 pk = *(const uint2*)(v + ((size_t)cj << 6) + (g << 2));
        a0 = fmaf(wj, __uint_as_float(pk.x << 16), a0);
        a1 = fmaf(wj, __uint_as_float(pk.x & 0xffff0000u), a1);
        a2 = fmaf(wj, __uint_as_float(pk.y << 16), a2);
        a3 = fmaf(wj, __uint_as_float(pk.y & 0xffff0000u), a3);
      }
    }

    // epilogue: denom reduce within quarter, stats, store
#pragma unroll
    for (int mm = 1; mm < 16; mm <<= 1) dl += __shfl_xor(dl, mm, 64);
    float inv = __builtin_amdgcn_rcpf(dl);
    float o0 = a0 * inv, o1 = a1 * inv, o2 = a2 * inv, o3 = a3 * inv;
    float t0 = o0 + o1 + o2 + o3;
    float t1 = o0 * o0 + o1 * o1 + o2 * o2 + o3 * o3;
#pragma unroll
    for (int mm = 1; mm < 16; mm <<= 1) {
      t0 += __shfl_xor(t0, mm, 64);
      t1 += __shfl_xor(t1, mm, 64);
    }
    float var = (t1 - t0 * t0 * (1.0f / 64.f)) * (1.0f / 63.f);
    float isd = __builtin_amdgcn_rsqf(var);
    int cnode = grp * 4 + q;
    if (cnode < n) {
      float4 r = {o0 * isd, o1 * isd, o2 * isd, o3 * isd};
      *(float4*)&out[(size_t)cnode * 64 + (g << 2)] = r;
    }
  }
}

extern "C" void kernel_launch(void* const* d_in, const int* in_sizes, int n_in,
                              void* d_out, int out_size, void* d_ws, size_t ws_size,
                              hipStream_t stream) {
  const float* h = (const float*)d_in[0];
  const int* ei = (const int*)d_in[1];
  const float* W11 = (const float*)d_in[2];
  const float* b11 = (const float*)d_in[3];
  const float* W12 = (const float*)d_in[4];  // [1,64] -> 64-vec
  const float* b12 = (const float*)d_in[5];
  const float* W13 = (const float*)d_in[6];
  const float* b13 = (const float*)d_in[7];
  const float* W21 = (const float*)d_in[8];
  const float* b21 = (const float*)d_in[9];
  const float* W22 = (const float*)d_in[10];
  const float* b22 = (const float*)d_in[11];
  const float* W23 = (const float*)d_in[12];
  const float* b23 = (const float*)d_in[13];

  const int N = in_sizes[0] / 128;  // 100000
  const int E = in_sizes[1] / 2;    // 1600000
  const int* src = ei;
  const int* dst = ei + E;
  const int NB = (N + BIN_NODES - 1) >> BIN_SHIFT;  // 782

  // workspace carve-up (~48 MB)
  char* p = (char*)d_ws;
  auto alloc = [&](size_t bytes) -> void* {
    void* r = (void*)p;
    p += (bytes + WS_ALIGN - 1) / WS_ALIGN * WS_ALIGN;
    return r;
  };
  int* cursor = (int*)alloc((size_t)NB * 4);
  int* binned = (int*)alloc((size_t)NB * BIN_CAP * 4);  // 8.0MB
  int* rsb = (int*)alloc((size_t)N * 4);
  int* reb = (int*)alloc((size_t)N * 4);
  float* sbuf = (float*)alloc((size_t)N * 4);
  unsigned short* vbuf = (unsigned short*)alloc((size_t)N * 64 * 2);  // bf16
  float* out1 = (float*)alloc((size_t)N * 64 * 4);
  short* Wh1 = (short*)alloc(128 * 128 * 2);
  short* Wl1 = (short*)alloc(128 * 128 * 2);
  short* Wh2 = (short*)alloc(128 * 64 * 2);
  short* Wl2 = (short*)alloc(128 * 64 * 2);

  // ---- setup: weight prep (both layers) + cursor init, one launch ----
  k_setup<<<(24576 + NB + 255) / 256, 256, 0, stream>>>(
      W11, W13, Wh1, Wl1, W21, W23, Wh2, Wl2, cursor, NB);

  // ---- CSR build via bin sort (reused by both layers) ----
  k_bin<<<(E + EPB - 1) / EPB, 256, 0, stream>>>(src, dst, cursor, binned, E, NB);
  k_sort_bin<<<NB, 256, 0, stream>>>(binned, cursor, rsb, reb, N);

  // ---- layer 1 (K=128) ----
  k_node<128><<<(N + 63) / 64, 256, 0, stream>>>(h, Wh1, Wl1, b11, W12, b13, vbuf, sbuf, N);
  k_aggr<<<AGGR_BLOCKS, 256, 0, stream>>>(rsb, reb, binned, sbuf, b12, vbuf, out1, N);

  // ---- layer 2 (K=64) ----
  k_node<64><<<(N + 63) / 64, 256, 0, stream>>>(out1, Wh2, Wl2, b21, W22, b23, vbuf, sbuf, N);
  k_aggr<<<AGGR_BLOCKS, 256, 0, stream>>>(rsb, reb, binned, sbuf, b22, vbuf, (float*)d_out, N);
}

// Round 7
// 285.643 us; speedup vs baseline: 1.0506x; 1.0506x over previous
//
#include <hip/hip_runtime.h>

// GAT 2-layer, N=100000 nodes, E=1.6M edges, dims 128->64->64, all fp32.
// Strategy:
//   - s[i] = a[i]·we collapses edge-logit GEMV to per-node scalar (We is [1,64]).
//   - tanh-bounded logits => skip segment_max (exp ratio identical).
//   - CSR build: coarse 128-node-bin counting sort + per-bin in-LDS sort.
//     R9: within-node DETERMINISTIC order (rank-sort by dst).
//   - k_node v2 (R13): register-stationary W frags, pre-converted bf16 hi/lo
//     LDS x-tile; inner loop = ds_read_b128 + MFMA only.
//   - k_aggr v10 (R15): R6's 32-burst regressed ONLY because
//     __launch_bounds__(256,4) clamped VGPR to 64 -> pv/pw spilled to scratch
//     (WRITE_SIZE 25->60MB proves it). Same structure, unclamped registers
//     (~130 VGPR, still 4 waves/SIMD) + back to 2048 blocks:
//       * 32 outstanding v-row gathers per wave, held in registers
//       * both edge-slots' col + s[col] prefetched one group ahead
//       * deg>32 fallback (~2e-5) keeps exact per-node accumulation order

#define WS_ALIGN 256
#define BIN_SHIFT 7
#define BIN_NODES 128
#define BIN_CAP 2560   // mean bin count 2048, sigma ~44 -> +11.6 sigma margin
#define MAX_BINS 1024
#define EPB 4096       // edges per k_bin block
#define AGGR_BLOCKS 2048

typedef __attribute__((ext_vector_type(8))) short short8;
typedef __attribute__((ext_vector_type(4))) short short4_t;
typedef __attribute__((ext_vector_type(4))) float f32x4;

__device__ __forceinline__ float fast_tanh(float x) {
  x = fminf(15.f, fmaxf(-15.f, x));
  float e = __expf(2.f * x);
  return (e - 1.f) * __builtin_amdgcn_rcpf(e + 1.f);
}

__device__ __forceinline__ unsigned short f32_to_bf16_rne(float f) {
  unsigned u = __float_as_uint(f);
  unsigned r = u + 0x7fffu + ((u >> 16) & 1u);
  return (unsigned short)(r >> 16);
}

// Split one element of [Wa;Wv] into bf16 hi/lo, FRAGMENT-LINEAR layout:
// i = (((nt*KBLK + kb)*4 + q)*16 + c)*8 + j  <->  W[nt*16+c][kb*32+q*8+j].
__device__ __forceinline__ void prepw_one(const float* __restrict__ Wa,
                                          const float* __restrict__ Wv,
                                          short* __restrict__ Wh, short* __restrict__ Wl,
                                          int K, int i) {
  int KBLK = K / 32;
  int j = i & 7;
  int c = (i >> 3) & 15;
  int q = (i >> 7) & 3;
  int r = i >> 9;  // nt*KBLK + kb
  int nt = r / KBLK, kb = r - nt * KBLK;
  int row = nt * 16 + c;
  int col = kb * 32 + q * 8 + j;
  float f = (row < 64) ? Wa[row * K + col] : Wv[(row - 64) * K + col];
  unsigned u = __float_as_uint(f);
  float hf = __uint_as_float(u & 0xffff0000u);
  Wh[i] = (short)(u >> 16);
  Wl[i] = (short)(__float_as_uint(f - hf) >> 16);
}

// Fused setup: weight prep for both layers + cursor init (one launch).
__global__ void k_setup(const float* __restrict__ W11, const float* __restrict__ W13,
                        short* __restrict__ Wh1, short* __restrict__ Wl1,
                        const float* __restrict__ W21, const float* __restrict__ W23,
                        short* __restrict__ Wh2, short* __restrict__ Wl2,
                        int* __restrict__ cursor, int nb) {
  int i = blockIdx.x * 256 + threadIdx.x;
  if (i < 16384) {
    prepw_one(W11, W13, Wh1, Wl1, 128, i);
  } else if (i < 16384 + 8192) {
    prepw_one(W21, W23, Wh2, Wl2, 64, i - 16384);
  } else {
    int b = i - 24576;
    if (b < nb) cursor[b] = b * BIN_CAP;
  }
}

// Coarse counting-sort of edges into 128-node bins.
__global__ __launch_bounds__(256) void k_bin(const int* __restrict__ src,
                                             const int* __restrict__ dst,
                                             int* __restrict__ cursor,
                                             int* __restrict__ binned, int E, int nb) {
  __shared__ int ssrc[EPB];
  __shared__ int sdst[EPB];
  __shared__ int hist[MAX_BINS];
  __shared__ int base[MAX_BINS];
  int t = threadIdx.x;
  for (int i = t; i < nb; i += 256) hist[i] = 0;
  __syncthreads();
  int e0 = blockIdx.x * EPB;
  for (int i = t; i < EPB; i += 256) {
    int e = e0 + i;
    int sv = -1, dv = 0;
    if (e < E) {
      sv = src[e];
      dv = dst[e];
      atomicAdd(&hist[sv >> BIN_SHIFT], 1);
    }
    ssrc[i] = sv;
    sdst[i] = dv;
  }
  __syncthreads();
  for (int b = t; b < nb; b += 256) {
    int c = hist[b];
    base[b] = c ? atomicAdd(&cursor[b], c) : 0;
    hist[b] = 0;
  }
  __syncthreads();
  for (int i = t; i < EPB; i += 256) {
    int sv = ssrc[i];
    if (sv >= 0) {
      int b = sv >> BIN_SHIFT;
      int r = atomicAdd(&hist[b], 1);
      int pos = base[b] + r;
      if (pos < (b + 1) * BIN_CAP)  // overflow guard (never expected to fire)
        binned[pos] = (sdst[i] << BIN_SHIFT) | (sv & (BIN_NODES - 1));
    }
  }
}

// One block per bin: group by src-within-bin in LDS (counting sort), then
// DETERMINISTIC rank-sort of each node's segment by dst (atomic scatter order
// is launch-dependent; sorted multiset is not). Coalesced write-back of
// dst-only values, emit per-node [rs, re).
__global__ __launch_bounds__(256) void k_sort_bin(int* __restrict__ binned,
                                                  const int* __restrict__ cursor,
                                                  int* __restrict__ rs,
                                                  int* __restrict__ re, int n) {
  __shared__ int ents[BIN_CAP];    // input pk; reused as rank-sorted dst output
  __shared__ int sorted[BIN_CAP];  // node-grouped pk
  __shared__ int hist[BIN_NODES];
  __shared__ int scan[BIN_NODES];
  __shared__ int cur[BIN_NODES];
  int bin = blockIdx.x;
  int t = threadIdx.x;
  int nbase = bin << BIN_SHIFT;
  int cnt = cursor[bin] - bin * BIN_CAP;
  if (cnt > BIN_CAP) cnt = BIN_CAP;
  if (t < BIN_NODES) hist[t] = 0;
  __syncthreads();
  int* bp = binned + (size_t)bin * BIN_CAP;
  for (int i = t; i < cnt; i += 256) {
    int pk = bp[i];
    ents[i] = pk;
    atomicAdd(&hist[pk & (BIN_NODES - 1)], 1);
  }
  __syncthreads();
  if (t < BIN_NODES) scan[t] = hist[t];
  __syncthreads();
  for (int off = 1; off < BIN_NODES; off <<= 1) {
    int add = (t < BIN_NODES && t >= off) ? scan[t - off] : 0;
    __syncthreads();
    if (t < BIN_NODES) scan[t] += add;
    __syncthreads();
  }
  if (t < BIN_NODES) {
    int ex = scan[t] - hist[t];  // exclusive
    cur[t] = ex;
    int node = nbase + t;
    if (node < n) {
      rs[node] = bin * BIN_CAP + ex;
      re[node] = bin * BIN_CAP + ex + hist[t];
    }
  }
  __syncthreads();
  // scatter by node (keep full pk — needed for the rank pass)
  for (int i = t; i < cnt; i += 256) {
    int pk = ents[i];
    int pos = atomicAdd(&cur[pk & (BIN_NODES - 1)], 1);
    sorted[pos] = pk;
  }
  __syncthreads();
  // deterministic rank-sort within each node segment, ascending by dst.
  for (int i = t; i < cnt; i += 256) {
    int pk = sorted[i];
    int node = pk & (BIN_NODES - 1);
    int hi = scan[node];
    int lo = hi - hist[node];
    int r = lo;
    for (int j = lo; j < hi; j++) {
      int pj = sorted[j];
      r += (pj < pk) || (pj == pk && j < i);
    }
    ents[r] = pk >> BIN_SHIFT;  // keep dst only
  }
  __syncthreads();
  for (int i = t; i < cnt; i += 256) bp[i] = ents[i];  // coalesced write-back
}

// MFMA node kernel v2: D[node][0..127] = x[node][:] @ [Wa;Wv]^T, 16x16x32 bf16.
// Block = 256 thr / 4 waves / 64 nodes. Wave w owns output n-tiles {2w,2w+1}
// (32 dims) with W frags REGISTER-STATIONARY (one-time coalesced loads);
// iterates 4 node-subtiles from a pre-converted bf16 hi/lo LDS x-tile
// (+8-short row pad -> only free 2-way conflicts on ds_read_b128).
// Waves 0,1 hold a-dims -> partial s, combined via sP LDS; waves 2,3 write v.
template <int K>
__global__ __launch_bounds__(256) void k_node(
    const float* __restrict__ x, const short* __restrict__ Wh,
    const short* __restrict__ Wl, const float* __restrict__ ba,
    const float* __restrict__ we, const float* __restrict__ bv,
    unsigned short* __restrict__ v_out, float* __restrict__ s_out, int n) {
  constexpr int KBLK = K / 32;
  constexpr int RS = K + 8;  // shorts per LDS row (+16B pad)
  __shared__ short sah[64 * RS];
  __shared__ short sal[64 * RS];
  __shared__ float sP[2][64];
  int t = threadIdx.x;
  int l = t & 63;
  int w = t >> 6;
  int q = l >> 4, c = l & 15;
  int node0b = blockIdx.x * 64;

  // stage x tile: coalesced float4 read -> bf16 hi/lo split -> LDS
  {
    const float4* xg = (const float4*)(x + (size_t)node0b * K);
    constexpr int R4 = K / 4;
#pragma unroll
    for (int it = 0; it < 64 * R4 / 256; it++) {
      int i = it * 256 + t;
      int r = i / R4, k4 = i - r * R4;
      float4 val = (node0b + r < n) ? xg[i] : (float4){0.f, 0.f, 0.f, 0.f};
      float xv[4] = {val.x, val.y, val.z, val.w};
      short4_t hi, lo;
#pragma unroll
      for (int j = 0; j < 4; j++) {
        unsigned u = __float_as_uint(xv[j]);
        hi[j] = (short)(u >> 16);
        float hf = __uint_as_float(u & 0xffff0000u);
        lo[j] = (short)(__float_as_uint(xv[j] - hf) >> 16);
      }
      *(short4_t*)&sah[r * RS + k4 * 4] = hi;
      *(short4_t*)&sal[r * RS + k4 * 4] = lo;
    }
  }

  // one-time W fragment loads (register-stationary), overlap staging wait
  const short8* WhF = (const short8*)Wh;
  const short8* WlF = (const short8*)Wl;
  short8 wfh[2][KBLK], wfl[2][KBLK];
#pragma unroll
  for (int mt = 0; mt < 2; mt++)
#pragma unroll
    for (int kb = 0; kb < KBLK; kb++) {
      size_t f = (size_t)((2 * w + mt) * KBLK + kb) * 64 + l;
      wfh[mt][kb] = WhF[f];
      wfl[mt][kb] = WlF[f];
    }
  __syncthreads();

  f32x4 acc[4][2];
#pragma unroll
  for (int ns = 0; ns < 4; ns++)
#pragma unroll
    for (int mt = 0; mt < 2; mt++) acc[ns][mt] = (f32x4){0.f, 0.f, 0.f, 0.f};

#pragma unroll
  for (int ns = 0; ns < 4; ns++) {
#pragma unroll
    for (int kb = 0; kb < KBLK; kb++) {
      int off = (ns * 16 + c) * RS + kb * 32 + q * 8;
      short8 ah = *(const short8*)&sah[off];
      short8 al = *(const short8*)&sal[off];
#pragma unroll
      for (int mt = 0; mt < 2; mt++) {
        acc[ns][mt] = __builtin_amdgcn_mfma_f32_16x16x32_bf16(ah, wfh[mt][kb], acc[ns][mt], 0, 0, 0);
        acc[ns][mt] = __builtin_amdgcn_mfma_f32_16x16x32_bf16(ah, wfl[mt][kb], acc[ns][mt], 0, 0, 0);
        acc[ns][mt] = __builtin_amdgcn_mfma_f32_16x16x32_bf16(al, wfh[mt][kb], acc[ns][mt], 0, 0, 0);
      }
    }
  }

  // ---- epilogue ----
  if (w < 2) {
    // a-dims: partial s over this wave's 32 dims
    float bav0 = ba[w * 32 + c], wev0 = we[w * 32 + c];
    float bav1 = ba[w * 32 + 16 + c], wev1 = we[w * 32 + 16 + c];
#pragma unroll
    for (int ns = 0; ns < 4; ns++) {
#pragma unroll
      for (int r = 0; r < 4; r++) {
        float pv = fast_tanh(acc[ns][0][r] + bav0) * wev0 +
                   fast_tanh(acc[ns][1][r] + bav1) * wev1;
#pragma unroll
        for (int mm = 1; mm < 16; mm <<= 1) pv += __shfl_xor(pv, mm, 64);
        if (c == 0) sP[w][ns * 16 + q * 4 + r] = pv;
      }
    }
  } else {
    // v-dims: write bf16 v
    int wv = w - 2;
    float bvv0 = bv[wv * 32 + c], bvv1 = bv[wv * 32 + 16 + c];
#pragma unroll
    for (int ns = 0; ns < 4; ns++) {
#pragma unroll
      for (int r = 0; r < 4; r++) {
        int node = node0b + ns * 16 + q * 4 + r;
        if (node < n) {
          v_out[(size_t)node * 64 + wv * 32 + c] =
              f32_to_bf16_rne(fast_tanh(acc[ns][0][r] + bvv0));
          v_out[(size_t)node * 64 + wv * 32 + 16 + c] =
              f32_to_bf16_rne(fast_tanh(acc[ns][1][r] + bvv1));
        }
      }
    }
  }
  __syncthreads();
  if (t < 64) {
    int node = node0b + t;
    if (node < n) s_out[node] = sP[0][t] + sP[1][t];
  }
}

// k_aggr v10: 4 nodes per wave, lane = (node-slot q=l>>4, dim-group g=l&15).
// Per group ONE 32-edge-per-node burst: 16 gathers always + 16 when any node
// has deg>16 (wave-uniform) -> up to 32 outstanding v-row gathers held in
// REGISTERS (no launch_bounds clamp; R6's spill lesson). Both slots' col +
// s[col] prefetched one group ahead. deg>32 fallback keeps exact order.
__global__ __launch_bounds__(256) void k_aggr(const int* __restrict__ rs,
                                              const int* __restrict__ re,
                                              const int* __restrict__ col,
                                              const float* __restrict__ s,
                                              const float* __restrict__ be_p,
                                              const unsigned short* __restrict__ v,
                                              float* __restrict__ out, int n) {
  int wid = (int)((blockIdx.x * 256 + threadIdx.x) >> 6);
  int nwv = (int)gridDim.x * 4;
  int l = threadIdx.x & 63;
  int q = l >> 4;  // node slot 0..3
  int g = l & 15;  // dim group: dims g*4 .. g*4+3 ; also edge sub-index
  int qb = l & 48; // quarter base lane
  float be = be_p[0];
  int ngroups = (n + 3) >> 2;
  if (wid >= ngroups) return;

  // prefetched state for the current group (meta, both edge slots)
  int ce0, ce1;
  float csrow, csc0, csc1;
  int cc0, cc1;
  {
    int node = wid * 4 + q;
    bool vn = node < n;
    ce0 = vn ? rs[node] : 0;
    ce1 = vn ? re[node] : 0;
    csrow = vn ? s[node] : 0.f;
    int m = ce1 - ce0;
    cc0 = (g < m) ? col[ce0 + g] : 0;
    cc1 = (g + 16 < m) ? col[ce0 + g + 16] : 0;
    csc0 = (g < m) ? s[cc0] : 0.f;
    csc1 = (g + 16 < m) ? s[cc1] : 0.f;
  }

  for (int grp = wid; grp < ngroups; grp += nwv) {
    int m = ce1 - ce0;
    int e0 = ce0;
    float srow = csrow;
    bool two = __any(m > 16);  // wave-uniform: second burst needed?

    // burst 1: edges 0..15 of each node (16 gathers in flight)
    uint2 pv[16];
#pragma unroll
    for (int jj = 0; jj < 16; jj++) {
      int cj = __shfl(cc0, qb + jj, 64);
      pv[jj] = *(const uint2*)(v + ((size_t)cj << 6) + (g << 2));
    }
    // burst 2: edges 16..31 (guard lanes pull row 0 -> cached, w=0)
    uint2 pw[16];
    if (two) {
#pragma unroll
      for (int jj = 0; jj < 16; jj++) {
        int cj = __shfl(cc1, qb + jj, 64);
        pw[jj] = *(const uint2*)(v + ((size_t)cj << 6) + (g << 2));
      }
    }

    // weights for both slots (overlaps gather returns)
    float w0 = (g < m) ? __expf(fast_tanh(srow + csc0 + be)) : 0.f;
    float w1 = (g + 16 < m) ? __expf(fast_tanh(srow + csc1 + be)) : 0.f;
    float dl = w0 + w1;

    // prefetch next group's meta + cols + s[col] (overlaps consume)
    int nxt = grp + nwv;
    if (nxt < ngroups) {
      int node = nxt * 4 + q;
      bool vn = node < n;
      ce0 = vn ? rs[node] : 0;
      ce1 = vn ? re[node] : 0;
      csrow = vn ? s[node] : 0.f;
      int nm = ce1 - ce0;
      cc0 = (g < nm) ? col[ce0 + g] : 0;
      cc1 = (g + 16 < nm) ? col[ce0 + g + 16] : 0;
      csc0 = (g < nm) ? s[cc0] : 0.f;
      csc1 = (g + 16 < nm) ? s[cc1] : 0.f;
    }

    // consume burst 1 (edges 0..15, in order)
    float a0 = 0.f, a1 = 0.f, a2 = 0.f, a3 = 0.f;
#pragma unroll
    for (int jj = 0; jj < 16; jj++) {
      float wj = __shfl(w0, qb + jj, 64);
      a0 = fmaf(wj, __uint_as_float(pv[jj].x << 16), a0);
      a1 = fmaf(wj, __uint_as_float(pv[jj].x & 0xffff0000u), a1);
      a2 = fmaf(wj, __uint_as_float(pv[jj].y << 16), a2);
      a3 = fmaf(wj, __uint_as_float(pv[jj].y & 0xffff0000u), a3);
    }
    // consume burst 2 (edges 16..31, in order)
    if (two) {
#pragma unroll
      for (int jj = 0; jj < 16; jj++) {
        float wj = __shfl(w1, qb + jj, 64);
        a0 = fmaf(wj, __uint_as_float(pw[jj].x << 16), a0);
        a1 = fmaf(wj, __uint_as_float(pw[jj].x & 0xffff0000u), a1);
        a2 = fmaf(wj, __uint_as_float(pw[jj].y << 16), a2);
        a3 = fmaf(wj, __uint_as_float(pw[jj].y & 0xffff0000u), a3);
      }
    }
    // fallback for deg>32 (vanishingly rare; keeps exact order)
    for (int cb = 32; !__all(m - cb <= 0); cb += 16) {
      bool act = (cb + g) < m;
      int c = act ? col[e0 + cb + g] : 0;
      float wx = act ? __expf(fast_tanh(srow + s[c] + be)) : 0.f;
      dl += wx;
#pragma unroll
      for (int jj = 0; jj < 16; jj++) {
        int cj = __shfl(c, qb + jj, 64);
        float wj = __shfl(wx, qb + jj, 64);
        uint2 pk = *(const uint2*)(v + ((size_t)cj << 6) + (g << 2));
        a0 = fmaf(wj, __uint_as_float(pk.x << 16), a0);
        a1 = fmaf(wj, __uint_as_float(pk.x & 0xffff0000u), a1);
        a2 = fmaf(wj, __uint_as_float(pk.y << 16), a2);
        a3 = fmaf(wj, __uint_as_float(pk.y & 0xffff0000u), a3);
      }
    }

    // epilogue: denom reduce within quarter, stats, store
#pragma unroll
    for (int mm = 1; mm < 16; mm <<= 1) dl += __shfl_xor(dl, mm, 64);
    float inv = __builtin_amdgcn_rcpf(dl);
    float o0 = a0 * inv, o1 = a1 * inv, o2 = a2 * inv, o3 = a3 * inv;
    float t0 = o0 + o1 + o2 + o3;
    float t1 = o0 * o0 + o1 * o1 + o2 * o2 + o3 * o3;
#pragma unroll
    for (int mm = 1; mm < 16; mm <<= 1) {
      t0 += __shfl_xor(t0, mm, 64);
      t1 += __shfl_xor(t1, mm, 64);
    }
    float var = (t1 - t0 * t0 * (1.0f / 64.f)) * (1.0f / 63.f);
    float isd = __builtin_amdgcn_rsqf(var);
    int cnode = grp * 4 + q;
    if (cnode < n) {
      float4 r = {o0 * isd, o1 * isd, o2 * isd, o3 * isd};
      *(float4*)&out[(size_t)cnode * 64 + (g << 2)] = r;
    }
  }
}

extern "C" void kernel_launch(void* const* d_in, const int* in_sizes, int n_in,
                              void* d_out, int out_size, void* d_ws, size_t ws_size,
                              hipStream_t stream) {
  const float* h = (const float*)d_in[0];
  const int* ei = (const int*)d_in[1];
  const float* W11 = (const float*)d_in[2];
  const float* b11 = (const float*)d_in[3];
  const float* W12 = (const float*)d_in[4];  // [1,64] -> 64-vec
  const float* b12 = (const float*)d_in[5];
  const float* W13 = (const float*)d_in[6];
  const float* b13 = (const float*)d_in[7];
  const float* W21 = (const float*)d_in[8];
  const float* b21 = (const float*)d_in[9];
  const float* W22 = (const float*)d_in[10];
  const float* b22 = (const float*)d_in[11];
  const float* W23 = (const float*)d_in[12];
  const float* b23 = (const float*)d_in[13];

  const int N = in_sizes[0] / 128;  // 100000
  const int E = in_sizes[1] / 2;    // 1600000
  const int* src = ei;
  const int* dst = ei + E;
  const int NB = (N + BIN_NODES - 1) >> BIN_SHIFT;  // 782

  // workspace carve-up (~48 MB)
  char* p = (char*)d_ws;
  auto alloc = [&](size_t bytes) -> void* {
    void* r = (void*)p;
    p += (bytes + WS_ALIGN - 1) / WS_ALIGN * WS_ALIGN;
    return r;
  };
  int* cursor = (int*)alloc((size_t)NB * 4);
  int* binned = (int*)alloc((size_t)NB * BIN_CAP * 4);  // 8.0MB
  int* rsb = (int*)alloc((size_t)N * 4);
  int* reb = (int*)alloc((size_t)N * 4);
  float* sbuf = (float*)alloc((size_t)N * 4);
  unsigned short* vbuf = (unsigned short*)alloc((size_t)N * 64 * 2);  // bf16
  float* out1 = (float*)alloc((size_t)N * 64 * 4);
  short* Wh1 = (short*)alloc(128 * 128 * 2);
  short* Wl1 = (short*)alloc(128 * 128 * 2);
  short* Wh2 = (short*)alloc(128 * 64 * 2);
  short* Wl2 = (short*)alloc(128 * 64 * 2);

  // ---- setup: weight prep (both layers) + cursor init, one launch ----
  k_setup<<<(24576 + NB + 255) / 256, 256, 0, stream>>>(
      W11, W13, Wh1, Wl1, W21, W23, Wh2, Wl2, cursor, NB);

  // ---- CSR build via bin sort (reused by both layers) ----
  k_bin<<<(E + EPB - 1) / EPB, 256, 0, stream>>>(src, dst, cursor, binned, E, NB);
  k_sort_bin<<<NB, 256, 0, stream>>>(binned, cursor, rsb, reb, N);

  // ---- layer 1 (K=128) ----
  k_node<128><<<(N + 63) / 64, 256, 0, stream>>>(h, Wh1, Wl1, b11, W12, b13, vbuf, sbuf, N);
  k_aggr<<<AGGR_BLOCKS, 256, 0, stream>>>(rsb, reb, binned, sbuf, b12, vbuf, out1, N);

  // ---- layer 2 (K=64) ----
  k_node<64><<<(N + 63) / 64, 256, 0, stream>>>(out1, Wh2, Wl2, b21, W22, b23, vbuf, sbuf, N);
  k_aggr<<<AGGR_BLOCKS, 256, 0, stream>>>(rsb, reb, binned, sbuf, b22, vbuf, (float*)d_out, N);
}